// Round 2
// baseline (39.553 us; speedup 1.0000x reference)
//
#include <hip/hip_runtime.h>

// Problem constants (reference: shape (32, 3, 512, 512) float32).
#define HW       (512 * 512)        // 262144 elements per channel plane
#define NBATCH   32
#define NPIX     (NBATCH * HW)      // 8,388,608 pixels per tensor
#define NGROUP   (NPIX / 4)         // 2,097,152 float4 pixel-groups
#define NBLOCKS  4096
#define NTHREADS 256
#define TOTAL_T  (NBLOCKS * NTHREADS)   // 1,048,576 threads; 2 groups/thread

// s = (max-min)/max on rgb=(x+1)*0.5  ==  (mx-mn)/(mx+1) on raw x, 0 if mx+1==0
__device__ __forceinline__ float sat_raw(float r, float g, float b) {
    float mx = fmaxf(fmaxf(r, g), b);
    float mn = fminf(fminf(r, g), b);
    float vp = mx + 1.0f;
    return (vp > 0.0f) ? ((mx - mn) / vp) : 0.0f;
}

__device__ __forceinline__ float sat_diff4(
        const float4& ar, const float4& ag, const float4& ab,
        const float4& br, const float4& bg, const float4& bb) {
    float s = 0.0f;
    s += fabsf(sat_raw(ar.x, ag.x, ab.x) - sat_raw(br.x, bg.x, bb.x));
    s += fabsf(sat_raw(ar.y, ag.y, ab.y) - sat_raw(br.y, bg.y, bb.y));
    s += fabsf(sat_raw(ar.z, ag.z, ab.z) - sat_raw(br.z, bg.z, bb.z));
    s += fabsf(sat_raw(ar.w, ag.w, ab.w) - sat_raw(br.w, bg.w, bb.w));
    return s;
}

__global__ __launch_bounds__(NTHREADS) void sat_loss_partial(
        const float* __restrict__ gen,
        const float* __restrict__ tgt,
        float* __restrict__ partial) {
    const int tid = blockIdx.x * NTHREADS + threadIdx.x;   // 0 .. TOTAL_T-1

    // Two float4-groups per thread, strided by TOTAL_T (coalesced within wave).
    const int g0 = tid;
    const int g1 = tid + TOTAL_T;

    const long base0 = (long)(g0 >> 16) * (3L * HW) + ((long)(g0 & 65535) << 2);
    const long base1 = (long)(g1 >> 16) * (3L * HW) + ((long)(g1 & 65535) << 2);

    // Issue all 12 loads before any compute: 48 payload VGPRs of MLP.
    const float4 a0r = *(const float4*)(gen + base0);
    const float4 a0g = *(const float4*)(gen + base0 + HW);
    const float4 a0b = *(const float4*)(gen + base0 + 2L * HW);
    const float4 b0r = *(const float4*)(tgt + base0);
    const float4 b0g = *(const float4*)(tgt + base0 + HW);
    const float4 b0b = *(const float4*)(tgt + base0 + 2L * HW);
    const float4 a1r = *(const float4*)(gen + base1);
    const float4 a1g = *(const float4*)(gen + base1 + HW);
    const float4 a1b = *(const float4*)(gen + base1 + 2L * HW);
    const float4 b1r = *(const float4*)(tgt + base1);
    const float4 b1g = *(const float4*)(tgt + base1 + HW);
    const float4 b1b = *(const float4*)(tgt + base1 + 2L * HW);

    float acc = sat_diff4(a0r, a0g, a0b, b0r, b0g, b0b)
              + sat_diff4(a1r, a1g, a1b, b1r, b1g, b1b);

    // wave-64 reduce
    #pragma unroll
    for (int off = 32; off > 0; off >>= 1)
        acc += __shfl_down(acc, off, 64);

    __shared__ float wave_sum[NTHREADS / 64];
    const int lane = threadIdx.x & 63;
    const int wid  = threadIdx.x >> 6;
    if (lane == 0) wave_sum[wid] = acc;
    __syncthreads();

    if (threadIdx.x == 0) {
        float s = 0.0f;
        #pragma unroll
        for (int i = 0; i < NTHREADS / 64; ++i) s += wave_sum[i];
        partial[blockIdx.x] = s;
    }
}

__global__ __launch_bounds__(NTHREADS) void sat_loss_finalize(
        const float* __restrict__ partial,
        float* __restrict__ out) {
    float acc = 0.0f;
    for (int i = threadIdx.x; i < NBLOCKS; i += NTHREADS)
        acc += partial[i];

    #pragma unroll
    for (int off = 32; off > 0; off >>= 1)
        acc += __shfl_down(acc, off, 64);

    __shared__ float wave_sum[NTHREADS / 64];
    const int lane = threadIdx.x & 63;
    const int wid  = threadIdx.x >> 6;
    if (lane == 0) wave_sum[wid] = acc;
    __syncthreads();

    if (threadIdx.x == 0) {
        float s = 0.0f;
        #pragma unroll
        for (int i = 0; i < NTHREADS / 64; ++i) s += wave_sum[i];
        out[0] = s * (1.0f / (float)NPIX);   // WEIGHT == 1.0
    }
}

extern "C" void kernel_launch(void* const* d_in, const int* in_sizes, int n_in,
                              void* d_out, int out_size, void* d_ws, size_t ws_size,
                              hipStream_t stream) {
    const float* gen = (const float*)d_in[0];
    const float* tgt = (const float*)d_in[1];
    float* out = (float*)d_out;
    float* partial = (float*)d_ws;   // NBLOCKS floats = 16 KiB of scratch

    sat_loss_partial<<<NBLOCKS, NTHREADS, 0, stream>>>(gen, tgt, partial);
    sat_loss_finalize<<<1, NTHREADS, 0, stream>>>(partial, out);
}